// Round 14
// baseline (17106.097 us; speedup 1.0000x reference)
//
#include <hip/hip_runtime.h>

// ---------------------------------------------------------------------------
// FastCASSBlock v14: three-tier weight residency for the GRU scan.
// Capacity law (measured r3-r13): VGPR grant = 65536/threads (256KB/CU file);
// whh = 384KB/WG can NEVER be fully resident. Partition per thread (512 thr,
// thread=(K-half p, unit u), 48 uvec4 of weights): REG 20 (pinned, reloaded
// per chunk -- v13-proven pattern), LDS 14 (112KB, preloaded once), STREAM 14
// (224B/thread/step from L2, laundered so loads re-issue per step).
// Recurrence on VALU dot2 (2 waves/SIMD hides latency); input-proj chunk GEMM
// (CH=16) on the MFMA pipe; gates: p=1 deposits partials, p=0 finishes.
// Workspace (~98 MiB):
//   xn    f16 [65536,256]   @ 0          (33554432)
//   gray  f32 [65536]       @ 33554432   (262144)
//   flag  i32 [16]          @ 33816576   (256)
//   whhREG uvec4[2*512][20] @ 33816832   (327680)
//   whhLDS uvec4[2*14][512] @ 34144512   (229376)
//   whhSTR uvec4[2*512][14] @ 34373888   (229376)
//   out_w f16 [256,512]     @ 34603264   (262144)
//   wcomb f16 [1536,256]    @ 34865408   (786432)
//   badj  f32 [1536]        @ 35651840   (6144)
//   ycat  f16 [65536,512]   @ 35658240   (67108864)
// ---------------------------------------------------------------------------

#define L_   4096
#define CH   16     // scan chunk length (steps)
#define NCH  256    // L_/CH

typedef __attribute__((ext_vector_type(8))) _Float16 half8;
typedef __attribute__((ext_vector_type(2))) _Float16 half2v;
typedef __attribute__((ext_vector_type(4))) float f32x4;
typedef __attribute__((ext_vector_type(4))) unsigned uvec4;

__device__ __forceinline__ unsigned short f2h(float f) {
  _Float16 h = (_Float16)f;
  return __builtin_bit_cast(unsigned short, h);
}
__device__ __forceinline__ float h2f(unsigned short u) {
  return (float)__builtin_bit_cast(_Float16, u);
}
__device__ __forceinline__ float sigm(float x) {
  return __builtin_amdgcn_rcpf(1.f + __expf(-x));
}
__device__ __forceinline__ float tanhf_(float x) {
  return 1.f - 2.f * __builtin_amdgcn_rcpf(1.f + __expf(2.f * x));
}
__device__ __forceinline__ float dot2(unsigned w, unsigned h, float c) {
  return __builtin_amdgcn_fdot2(__builtin_bit_cast(half2v, w),
                                __builtin_bit_cast(half2v, h), c, false);
}

// --------------------------- f32 -> f16 convert ----------------------------
__global__ __launch_bounds__(256) void k_f2h(const float* __restrict__ in,
                                             unsigned short* __restrict__ out,
                                             int n) {
  int i = blockIdx.x * 256 + threadIdx.x;
  if (i < n) out[i] = f2h(in[i]);
}

// ---------------- pack whh into the three tiers (canonical order) ----------
// thread-owner t = p*256+u; canonical uvec4 #j (j<48): gate=j>>4, jj=j&15,
// src = whh_d[gate*256+u][p*128 + jj*8 .. +8].
// REG #0..19 -> whhREG[(d*512+t)*20 + j]
// LDS #20..33 -> whhLDS[(d*14+(j-20))*512 + t]
// STR #34..47 -> whhSTR[(d*512+t)*14 + (j-34)]
__global__ __launch_bounds__(64) void k_pack(const float* __restrict__ whh_f,
                                             const float* __restrict__ whh_b,
                                             uvec4* __restrict__ whhREG,
                                             uvec4* __restrict__ whhLDSg,
                                             uvec4* __restrict__ whhSTR) {
  const int dt = blockIdx.x;      // 0..1023 = d*512 + t
  const int d = dt >> 9;
  const int t = dt & 511;
  const int p = t >> 8, u = t & 255;
  const int j = threadIdx.x;
  if (j >= 48) return;
  const int gate = j >> 4, jj = j & 15;
  const float* src = (d ? whh_b : whh_f) + (long)(gate * 256 + u) * 256 + p * 128 + jj * 8;
  unsigned short h[8];
#pragma unroll
  for (int q = 0; q < 8; ++q) h[q] = f2h(src[q]);
  uvec4 v;
  v.x = (unsigned)h[0] | ((unsigned)h[1] << 16);
  v.y = (unsigned)h[2] | ((unsigned)h[3] << 16);
  v.z = (unsigned)h[4] | ((unsigned)h[5] << 16);
  v.w = (unsigned)h[6] | ((unsigned)h[7] << 16);
  if (j < 20)      whhREG[(long)dt * 20 + j] = v;
  else if (j < 34) whhLDSg[(long)(d * 14 + (j - 20)) * 512 + t] = v;
  else             whhSTR[(long)dt * 14 + (j - 34)] = v;
}

// ------------------- wcomb[n,c] = sum_j wih[n,j]*in_w[j,c] -----------------
__global__ __launch_bounds__(256) void k_wcomb(const float* __restrict__ wih_f,
                                               const float* __restrict__ wih_b,
                                               const float* __restrict__ in_w,
                                               unsigned short* __restrict__ wcomb) {
  const int n = blockIdx.x;  // 0..1535
  const float* wrow = (n < 768) ? (wih_f + (long)n * 512)
                                : (wih_b + (long)(n - 768) * 512);
  const int k = threadIdx.x;  // 0..255
  float acc = 0.f;
  for (int j = 0; j < 512; ++j) acc += wrow[j] * in_w[j * 256 + k];
  wcomb[(long)n * 256 + k] = f2h(acc);
}

// -- badj[n] = bih[n] + sum_j wih[n,j]*in_b[j] (+ bhh[n] for r/z slots) ------
__global__ __launch_bounds__(256) void k_bcomb(const float* __restrict__ wih_f,
                                               const float* __restrict__ wih_b,
                                               const float* __restrict__ in_b,
                                               const float* __restrict__ bih_f,
                                               const float* __restrict__ bih_b,
                                               const float* __restrict__ bhh_f,
                                               const float* __restrict__ bhh_b,
                                               float* __restrict__ badj) {
  int n = blockIdx.x * 256 + threadIdx.x;
  if (n >= 1536) return;
  const int dir = n >= 768;
  const int g = dir ? (n - 768) : n;
  const float* wrow = (dir ? wih_b : wih_f) + (long)g * 512;
  float acc = (dir ? bih_b : bih_f)[g];
  for (int j = 0; j < 512; ++j) acc += wrow[j] * in_b[j];
  if (g < 512) acc += (dir ? bhh_b : bhh_f)[g];  // fold bhh for r,z gates
  badj[n] = acc;
}

// --------------------------- LayerNorm + gray ------------------------------
__global__ __launch_bounds__(256) void k_ln(const float* __restrict__ x,
                                            const float* __restrict__ gamma,
                                            const float* __restrict__ beta,
                                            unsigned short* __restrict__ xn,
                                            float* __restrict__ gray) {
  const int lane = threadIdx.x & 63;
  const long pix = (long)blockIdx.x * 4 + (threadIdx.x >> 6);
  const float4 v = *(const float4*)(x + pix * 256 + lane * 4);
  float s = v.x + v.y + v.z + v.w;
  float s2 = v.x * v.x + v.y * v.y + v.z * v.z + v.w * v.w;
#pragma unroll
  for (int off = 32; off > 0; off >>= 1) {
    s += __shfl_xor(s, off, 64);
    s2 += __shfl_xor(s2, off, 64);
  }
  const float mu = s * (1.f / 256.f);
  const float var = fmaxf(s2 * (1.f / 256.f) - mu * mu, 0.f);
  const float rstd = rsqrtf(var + 1e-5f);
  const float4 gm = *(const float4*)(gamma + lane * 4);
  const float4 bt = *(const float4*)(beta + lane * 4);
  float o0 = (v.x - mu) * rstd * gm.x + bt.x;
  float o1 = (v.y - mu) * rstd * gm.y + bt.y;
  float o2 = (v.z - mu) * rstd * gm.z + bt.z;
  float o3 = (v.w - mu) * rstd * gm.w + bt.w;
  ushort4 o;
  o.x = f2h(o0); o.y = f2h(o1); o.z = f2h(o2); o.w = f2h(o3);
  *(ushort4*)(xn + pix * 256 + lane * 4) = o;
  float gs = o0 + o1 + o2 + o3;
#pragma unroll
  for (int off = 32; off > 0; off >>= 1) gs += __shfl_xor(gs, off, 64);
  if (lane == 0) gray[pix] = gs * (1.f / 256.f);
}

// --------------------- gradient-direction selector -------------------------
__device__ __forceinline__ int refl64(int m) {
  return m < 0 ? -m : (m > 63 ? 126 - m : m);
}

__global__ __launch_bounds__(256) void k_sel(const float* __restrict__ gray,
                                             const float* __restrict__ w1,
                                             const float* __restrict__ b1,
                                             const float* __restrict__ w2,
                                             const float* __restrict__ b2,
                                             int* __restrict__ flag) {
  __shared__ float g[64][65];
  __shared__ float part[4][4];
  const int b = blockIdx.x;
  const int tid = threadIdx.x;
  for (int r = 0; r < 16; ++r) {
    int p = tid + 256 * r;
    g[p >> 6][p & 63] = gray[(long)b * 4096 + p];
  }
  __syncthreads();
  const float S = 66.f / 64.f;
  float sh = 0.f, sv = 0.f, sd = 0.f, sa = 0.f;
  for (int rr = 0; rr < 16; ++rr) {
    int p = tid + 256 * rr;
    int h = p >> 6, w = p & 63;
    float srci = (h + 0.5f) * S - 0.5f;
    int i0 = (int)srci;
    float ai = srci - (float)i0;
    int i1 = i0 + 1; if (i1 > 65) i1 = 65;
    int r0 = refl64(i0 - 1), r1 = refl64(i1 - 1);
    int wl = w ? (w - 1) : 1;
    int wr2 = (w == 63) ? 62 : (w + 1);
    float GH0 = fabsf(g[r0][wr2] - g[r0][wl]);
    float GH1 = fabsf(g[r1][wr2] - g[r1][wl]);
    float ghr = GH0 + ai * (GH1 - GH0);
    float srcj = (w + 0.5f) * S - 0.5f;
    int j0 = (int)srcj;
    float aj = srcj - (float)j0;
    int j1 = j0 + 1; if (j1 > 65) j1 = 65;
    int c0 = refl64(j0 - 1), c1 = refl64(j1 - 1);
    int hu = h ? (h - 1) : 1;
    int hd = (h == 63) ? 62 : (h + 1);
    float GV0 = fabsf(g[hd][c0] - g[hu][c0]);
    float GV1 = fabsf(g[hd][c1] - g[hu][c1]);
    float gvr = GV0 + aj * (GV1 - GV0);
    float wt = ((h == 0 || h == 63) ? 2.f : 3.f) *
               ((w == 0 || w == 63) ? 2.f : 3.f);
    sh += wt * ghr;
    sv += wt * gvr;
    sd += wt * 0.5f * (ghr + gvr);
    sa += wt * fabsf(ghr - gvr);
  }
#pragma unroll
  for (int off = 32; off > 0; off >>= 1) {
    sh += __shfl_xor(sh, off, 64);
    sv += __shfl_xor(sv, off, 64);
    sd += __shfl_xor(sd, off, 64);
    sa += __shfl_xor(sa, off, 64);
  }
  if ((tid & 63) == 0) {
    part[tid >> 6][0] = sh; part[tid >> 6][1] = sv;
    part[tid >> 6][2] = sd; part[tid >> 6][3] = sa;
  }
  __syncthreads();
  if (tid == 0) {
    float sc[4];
    for (int k = 0; k < 4; ++k)
      sc[k] = (part[0][k] + part[1][k] + part[2][k] + part[3][k]) * (1.f / 36864.f);
    float logits[4];
    for (int k = 0; k < 4; ++k) logits[k] = b2[k];
    for (int j = 0; j < 32; ++j) {
      float hj = b1[j];
      for (int i = 0; i < 4; ++i) hj += sc[i] * w1[j * 4 + i];
      hj = fmaxf(hj, 0.f);
      for (int k = 0; k < 4; ++k) logits[k] += hj * w2[k * 32 + j];
    }
    int idx = 0;
    float best = logits[0];
    for (int k = 1; k < 4; ++k)
      if (logits[k] > best) { best = logits[k]; idx = k; }
    flag[b] = (idx == 1) ? 1 : 0;
  }
}

// --------------------------- out-proj GEMM ---------------------------------
__global__ __launch_bounds__(256) void k_gemm(const unsigned short* __restrict__ A,
                                              const unsigned short* __restrict__ Bw,
                                              const float* __restrict__ bias,
                                              const float* __restrict__ resid,
                                              float* __restrict__ out,
                                              int K, int N) {
  __shared__ unsigned short Al[128][40];
  __shared__ unsigned short Bl[128][40];
  const int tid = threadIdx.x;
  const long m0 = (long)blockIdx.x * 128;
  const int n0 = blockIdx.y * 128;
  const int rA = tid >> 2;
  const int cp = (tid & 3) * 8;

  const unsigned short* a0p = A + (m0 + rA) * K + cp;
  const unsigned short* a1p = A + (m0 + rA + 64) * K + cp;
  const unsigned short* b0p = Bw + (long)(n0 + rA) * K + cp;
  const unsigned short* b1p = Bw + (long)(n0 + rA + 64) * K + cp;

  const int wv = tid >> 6, lane = tid & 63;
  const int wm = (wv >> 1) * 64, wn = (wv & 1) * 64;
  const int fr = lane & 15, fq = lane >> 4;

  const f32x4 zero4 = {0.f, 0.f, 0.f, 0.f};
  f32x4 acc[4][4];
#pragma unroll
  for (int i = 0; i < 4; ++i)
#pragma unroll
    for (int j = 0; j < 4; ++j) acc[i][j] = zero4;

  for (int k0 = 0; k0 < K; k0 += 32) {
    half8 va0 = *(const half8*)(a0p + k0);
    half8 va1 = *(const half8*)(a1p + k0);
    half8 vb0 = *(const half8*)(b0p + k0);
    half8 vb1 = *(const half8*)(b1p + k0);
    __syncthreads();
    *(half8*)&Al[rA][cp] = va0;
    *(half8*)&Al[rA + 64][cp] = va1;
    *(half8*)&Bl[rA][cp] = vb0;
    *(half8*)&Bl[rA + 64][cp] = vb1;
    __syncthreads();
    half8 af[4], bf[4];
#pragma unroll
    for (int i = 0; i < 4; ++i) af[i] = *(const half8*)&Al[wm + i * 16 + fr][fq * 8];
#pragma unroll
    for (int j = 0; j < 4; ++j) bf[j] = *(const half8*)&Bl[wn + j * 16 + fr][fq * 8];
#pragma unroll
    for (int i = 0; i < 4; ++i)
#pragma unroll
      for (int j = 0; j < 4; ++j)
        acc[i][j] = __builtin_amdgcn_mfma_f32_16x16x32_f16(af[i], bf[j], acc[i][j], 0, 0, 0);
  }

#pragma unroll
  for (int j = 0; j < 4; ++j) {
    const int col = n0 + wn + j * 16 + fr;
    const float bv = bias[col];
#pragma unroll
    for (int i = 0; i < 4; ++i) {
      const long mbase = m0 + wm + i * 16 + fq * 4;
#pragma unroll
      for (int r = 0; r < 4; ++r) {
        const long m = mbase + r;
        out[m * N + col] = acc[i][j][r] + bv + resid[m * N + col];
      }
    }
  }
}

// ------------------------------- GRU scan v14 -------------------------------
// 32 WGs (batch,dir) x 512 threads (8 waves, 2/SIMD). Thread (p,u): unit u,
// K-half p. Weights: REG tier 20 named pinned uvec4 (reloaded per chunk),
// LDS tier wlds[14][512] (preloaded once), STREAM tier 14 uvec4/step from L2
// (laundered base -> re-issued per step, per-thread contiguous, imm offsets).
// Both halves compute partial r/z/n dots; p=1 deposits partials in LDS;
// p=0 finishes gates in-thread and writes h (dbuf) + y. 2 barriers/step.
__global__ __launch_bounds__(512, 1) void k_scan(
    const unsigned short* __restrict__ xn,
    const unsigned short* __restrict__ wcomb,
    const float* __restrict__ badj,
    const uvec4* __restrict__ whhREG,
    const uvec4* __restrict__ whhLDSg,
    const uvec4* __restrict__ whhSTR,
    const float* __restrict__ bhhf,
    const float* __restrict__ bhhb,
    const int* __restrict__ flag,
    unsigned short* __restrict__ ycat) {
  const int dir = blockIdx.x & 1;
  const int b = blockIdx.x >> 1;
  const float* bhh = dir ? bhhb : bhhf;
  const unsigned short* wcd = wcomb + (long)dir * (768 * 256);
  const float* bcd = badj + dir * 768;
  const int tid = threadIdx.x;
  const int wv = tid >> 6;        // 0..7
  const int lane = tid & 63;
  const int fr = lane & 15;
  const int fq = lane >> 4;
  const int p = tid >> 8;         // K-half
  const int u = tid & 255;        // unit
  const int fb = flag[b];

  __shared__ unsigned short xplds[CH][768];   // 24 KiB
  __shared__ unsigned short ylds[CH][256];    // 8 KiB
  __shared__ uvec4 wlds[14][512];             // 112 KiB (LDS weight tier)
  __shared__ uvec4 hl4[2][32];                // 1 KiB  (h double-buffer)
  __shared__ float part[256][5];              // 5 KiB  (p=1 partials)

  // ---- one-time LDS weight preload ----
  {
    const uvec4* src = whhLDSg + (long)dir * (14 * 512);
#pragma unroll
    for (int i = 0; i < 14; ++i) wlds[i][tid] = src[i * 512 + tid];
  }
  const float Bnh = (p == 0) ? bhh[512 + u] : 0.f;
  float hreg = 0.f;
  if (tid < 128) ((unsigned*)hl4[0])[tid] = 0;
  __syncthreads();

  const long xnb = (long)b * 4096;
  unsigned short* yb = ycat + (long)b * (L_ * 512) + dir * 256;
  const uvec4* regp = whhREG + (long)(dir * 512 + tid) * 20;
  const uvec4* strp0 = whhSTR + (long)(dir * 512 + tid) * 14;

  const f32x4 zero4 = {0.f, 0.f, 0.f, 0.f};
  int pb = 0;

  for (int c = 0; c < NCH; ++c) {
    const int cc = dir ? (NCH - 1 - c) : c;
    const int t0 = cc * CH;

    // ---- flush previous chunk's y (one half8 per thread) ----
    if (c > 0) {
      const int pt0 = (dir ? (NCH - c) : (c - 1)) * CH;
      const int tsx = tid >> 5;
      const int cl = (tid & 31) * 8;
      half8 v = *(const half8*)&ylds[tsx][cl];
      *(half8*)(yb + (long)(pt0 + tsx) * 512 + cl) = v;
    }

    // ---- chunk GEMM (MFMA): xplds[0..15] = seq @ wcd.T + badj ----
    {
      const unsigned short* arow0;
      {
        int t = t0 + fr;
        int pp = fb ? (((t & 63) << 6) | (t >> 6)) : t;
        arow0 = xn + (xnb + pp) * 256 + fq * 8;
      }
#pragma unroll
      for (int hf = 0; hf < 2; ++hf) {
        f32x4 acc0[3];
#pragma unroll
        for (int i = 0; i < 3; ++i) acc0[i] = zero4;
#pragma unroll
        for (int s = 0; s < 8; ++s) {
          half8 a0v = *(const half8*)(arow0 + s * 32);
#pragma unroll
          for (int i = 0; i < 3; ++i) {
            const int jj = hf * 3 + i;
            const int n = (jj >> 1) * 256 + wv * 32 + (jj & 1) * 16 + fr;
            half8 bfr = *(const half8*)(wcd + (long)n * 256 + s * 32 + fq * 8);
            acc0[i] = __builtin_amdgcn_mfma_f32_16x16x32_f16(a0v, bfr, acc0[i], 0, 0, 0);
          }
        }
#pragma unroll
        for (int i = 0; i < 3; ++i) {
          const int jj = hf * 3 + i;
          const int n = (jj >> 1) * 256 + wv * 32 + (jj & 1) * 16 + fr;
          const float bv = bcd[n];
#pragma unroll
          for (int r = 0; r < 4; ++r)
            xplds[fq * 4 + r][n] = f2h(acc0[i][r] + bv);
        }
      }
    }
    __syncthreads();

    // ---- REG tier reload (laundered ptr, per chunk) + pin ----
    const uvec4* rp2 = regp;
    asm volatile("" : "+v"(rp2));
    uvec4 r00 = rp2[0],  r01 = rp2[1],  r02 = rp2[2],  r03 = rp2[3];
    uvec4 r04 = rp2[4],  r05 = rp2[5],  r06 = rp2[6],  r07 = rp2[7];
    uvec4 r08 = rp2[8],  r09 = rp2[9],  r10 = rp2[10], r11 = rp2[11];
    uvec4 r12 = rp2[12], r13 = rp2[13], r14 = rp2[14], r15 = rp2[15];
    uvec4 r16 = rp2[16], r17 = rp2[17], r18 = rp2[18], r19 = rp2[19];
    asm volatile("" : "+v"(r00), "+v"(r01), "+v"(r02), "+v"(r03),
                      "+v"(r04), "+v"(r05), "+v"(r06), "+v"(r07));
    asm volatile("" : "+v"(r08), "+v"(r09), "+v"(r10), "+v"(r11),
                      "+v"(r12), "+v"(r13), "+v"(r14), "+v"(r15));
    asm volatile("" : "+v"(r16), "+v"(r17), "+v"(r18), "+v"(r19));

    // ---- 16 sequential GRU steps ----
    for (int lt = 0; lt < CH; ++lt) {
      const int ts = dir ? (CH - 1 - lt) : lt;
      // laundered bases: force per-step re-issue (no LICM hoist)
      const uvec4* sp = strp0;
      asm volatile("" : "+v"(sp));
      int wb = 0;
      asm volatile("" : "+v"(wb));
      const uvec4* hp = &hl4[pb][p * 16];
      float ar0 = 0.f, ar1 = 0.f, az0 = 0.f, az1 = 0.f, an0 = 0.f, an1 = 0.f;
#define JSTEP(J, WR, ZEXPR, NEXPR)                       \
      {                                                  \
        uvec4 hv = hp[J];                                \
        uvec4 wz = (ZEXPR);                              \
        uvec4 wn = (NEXPR);                              \
        ar0 = dot2(WR.x, hv.x, ar0);                     \
        ar1 = dot2(WR.y, hv.y, ar1);                     \
        ar0 = dot2(WR.z, hv.z, ar0);                     \
        ar1 = dot2(WR.w, hv.w, ar1);                     \
        az0 = dot2(wz.x, hv.x, az0);                     \
        az1 = dot2(wz.y, hv.y, az1);                     \
        az0 = dot2(wz.z, hv.z, az0);                     \
        az1 = dot2(wz.w, hv.w, az1);                     \
        an0 = dot2(wn.x, hv.x, an0);                     \
        an1 = dot2(wn.y, hv.y, an1);                     \
        an0 = dot2(wn.z, hv.z, an0);                     \
        an1 = dot2(wn.w, hv.w, an1);                     \
      }
      JSTEP(0,  r00, r16,               wlds[wb + 12][tid])
      JSTEP(1,  r01, r17,               wlds[wb + 13][tid])
      JSTEP(2,  r02, r18,               sp[0])
      JSTEP(3,  r03, r19,               sp[1])
      JSTEP(4,  r04, wlds[wb + 0][tid], sp[2])
      JSTEP(5,  r05, wlds[wb + 1][tid], sp[3])
      JSTEP(6,  r06, wlds[wb + 2][tid], sp[4])
      JSTEP(7,  r07, wlds[wb + 3][tid], sp[5])
      JSTEP(8,  r08, wlds[wb + 4][tid], sp[6])
      JSTEP(9,  r09, wlds[wb + 5][tid], sp[7])
      JSTEP(10, r10, wlds[wb + 6][tid], sp[8])
      JSTEP(11, r11, wlds[wb + 7][tid], sp[9])
      JSTEP(12, r12, wlds[wb + 8][tid], sp[10])
      JSTEP(13, r13, wlds[wb + 9][tid], sp[11])
      JSTEP(14, r14, wlds[wb + 10][tid], sp[12])
      JSTEP(15, r15, wlds[wb + 11][tid], sp[13])
#undef JSTEP
      if (p == 1) {
        part[u][0] = ar0 + ar1;
        part[u][1] = az0 + az1;
        part[u][2] = an0 + an1;
      }
      __syncthreads();
      if (p == 0) {
        const float xr = h2f(xplds[ts][u]);
        const float xz = h2f(xplds[ts][256 + u]);
        const float xnv = h2f(xplds[ts][512 + u]);
        const float ghr = ar0 + ar1 + part[u][0];
        const float ghz = az0 + az1 + part[u][1];
        const float ghn = an0 + an1 + part[u][2];
        const float r = sigm(xr + ghr);
        const float z = sigm(xz + ghz);
        const float n = tanhf_(xnv + r * (ghn + Bnh));
        hreg = n + z * (hreg - n);
        const unsigned short hb = f2h(hreg);
        ((unsigned short*)hl4[pb ^ 1])[u] = hb;
        ylds[ts][u] = hb;
      }
      pb ^= 1;
      __syncthreads();
    }
  }
  // final chunk's y flush
  {
    const int pt0 = (dir ? 0 : (NCH - 1)) * CH;
    const int tsx = tid >> 5;
    const int cl = (tid & 31) * 8;
    half8 v = *(const half8*)&ylds[tsx][cl];
    *(half8*)(yb + (long)(pt0 + tsx) * 512 + cl) = v;
  }
}

// ------------------------------- launcher ----------------------------------
extern "C" void kernel_launch(void* const* d_in, const int* in_sizes, int n_in,
                              void* d_out, int out_size, void* d_ws, size_t ws_size,
                              hipStream_t stream) {
  (void)in_sizes; (void)n_in; (void)out_size; (void)ws_size;
  const float* x     = (const float*)d_in[0];
  const float* lng   = (const float*)d_in[1];
  const float* lnb   = (const float*)d_in[2];
  const float* w1    = (const float*)d_in[3];
  const float* b1    = (const float*)d_in[4];
  const float* w2    = (const float*)d_in[5];
  const float* b2    = (const float*)d_in[6];
  const float* in_w  = (const float*)d_in[7];
  const float* in_b  = (const float*)d_in[8];
  const float* wih_f = (const float*)d_in[9];
  const float* whh_f = (const float*)d_in[10];
  const float* bih_f = (const float*)d_in[11];
  const float* bhh_f = (const float*)d_in[12];
  const float* wih_b = (const float*)d_in[13];
  const float* whh_b = (const float*)d_in[14];
  const float* bih_b = (const float*)d_in[15];
  const float* bhh_b = (const float*)d_in[16];
  const float* out_w = (const float*)d_in[17];
  const float* out_b = (const float*)d_in[18];

  char* ws = (char*)d_ws;
  unsigned short* xn     = (unsigned short*)(ws + 0);
  float*          gray   = (float*)(ws + 33554432);
  int*            flag   = (int*)(ws + 33816576);
  uvec4*          whhREG = (uvec4*)(ws + 33816832);
  uvec4*          whhLDSg= (uvec4*)(ws + 34144512);
  uvec4*          whhSTR = (uvec4*)(ws + 34373888);
  unsigned short* outw16 = (unsigned short*)(ws + 34603264);
  unsigned short* wcomb  = (unsigned short*)(ws + 34865408);
  float*          badj   = (float*)(ws + 35651840);
  unsigned short* ycat   = (unsigned short*)(ws + 35658240);

  k_pack<<<1024, 64, 0, stream>>>(whh_f, whh_b, whhREG, whhLDSg, whhSTR);
  k_f2h<<<512, 256, 0, stream>>>(out_w, outw16, 131072);
  k_wcomb<<<1536, 256, 0, stream>>>(wih_f, wih_b, in_w, wcomb);
  k_bcomb<<<6, 256, 0, stream>>>(wih_f, wih_b, in_b, bih_f, bih_b,
                                 bhh_f, bhh_b, badj);
  k_ln<<<16384, 256, 0, stream>>>(x, lng, lnb, xn, gray);
  k_sel<<<16, 256, 0, stream>>>(gray, w1, b1, w2, b2, flag);
  k_scan<<<32, 512, 0, stream>>>(xn, wcomb, badj, whhREG, whhLDSg, whhSTR,
                                 bhh_f, bhh_b, flag, ycat);
  dim3 gout(512, 2);
  k_gemm<<<gout, 256, 0, stream>>>(ycat, outw16, out_b, x, (float*)d_out, 512, 256);
}